// Round 7
// baseline (514.090 us; speedup 1.0000x reference)
//
#include <hip/hip_runtime.h>

#define D_  256
#define K_  1024
#define HW_ 1024      // 32*32
#define N_  32768     // 32*HW_

// workspace layout (bytes)
#define WS_IDX     0          // int32[32768]
#define WS_COUNTS  131072     // f32[1024]
#define WS_EMBSUM  135168     // f32[262144]
#define WS_LOSS    1183744    // f32
#define WS_NSUM    1183748    // f32
#define WS_NEWCS   1183752    // f32[1024]
#define WS_ENORM   1187848    // f32[1024]
#define WS_ZNORM   1191944    // f32[32768]
#define WS_TOTAL   1323016

// output offsets (f32 elements): (z_q_st, loss, indices, new_emb, new_cs, new_es)
#define O_ZQ   0
#define O_LOSS 8388608
#define O_IDX  8388609
#define O_EMB  8421377
#define O_NCS  8683521
#define O_NES  8684545

// numpy pairwise_sum of 256 squares: two 128-halves, 8 accumulators,
// combine ((r0+r1)+(r2+r3))+((r4+r5)+(r6+r7)). __f*_rn blocks FMA contraction.
__device__ __forceinline__ float pw256_sq(const float* __restrict__ p, int stride) {
  float tot0 = 0.f, tot1 = 0.f;
#pragma unroll
  for (int h = 0; h < 2; ++h) {
    const float* q = p + h * 128 * stride;
    float r[8];
#pragma unroll
    for (int j = 0; j < 8; ++j) { float x = q[j * stride]; r[j] = __fmul_rn(x, x); }
    for (int i = 8; i < 128; i += 8)
#pragma unroll
      for (int j = 0; j < 8; ++j) {
        float x = q[(i + j) * stride];
        r[j] = __fadd_rn(r[j], __fmul_rn(x, x));
      }
    float s = __fadd_rn(__fadd_rn(__fadd_rn(r[0], r[1]), __fadd_rn(r[2], r[3])),
                        __fadd_rn(__fadd_rn(r[4], r[5]), __fadd_rn(r[6], r[7])));
    if (h == 0) tot0 = s; else tot1 = s;
  }
  return __fadd_rn(tot0, tot1);
}

// ---------------- ||z_n||^2 and ||e_k||^2, np summation order ----------------
__global__ void vq_norms_v7(const float* __restrict__ z, const float* __restrict__ E,
                            float* __restrict__ znorm, float* __restrict__ enorm) {
  int t = blockIdx.x * 128 + threadIdx.x;        // 264 x 128 = 33792
  if (t < N_) {
    const float* p = z + (t >> 10) * (D_ * HW_) + (t & 1023);  // stride HW_ over d
    znorm[t] = pw256_sq(p, HW_);
  } else if (t < N_ + K_) {
    enorm[t - N_] = pw256_sq(E + (t - N_) * D_, 1);
  }
}

// ---------------- fused distance-GEMM + argmin ----------------
// 1024 blocks (one per 32-token tile). Microtile 4 tok x 8 codes.
// Dot products: strict sequential-k FMA chain (matches BLAS sgemm microkernel
// rank-1-update order); (2z)@E.T == 2*(z@E.T) bit-exactly (pow2 scaling).
__global__ __launch_bounds__(256, 1) void vq_dist_v7(
    const float* __restrict__ z, const float* __restrict__ E,
    const float* __restrict__ znorm, const float* __restrict__ enorm,
    int* __restrict__ idx_out, float* __restrict__ counts) {
  __shared__ float zt[256 * 32];    // [d][t] stride 32 -> 32 KiB
  __shared__ float pv[32 * 33];
  __shared__ int   pi[32 * 33];
  const int tid = threadIdx.x;
  const int tile = blockIdx.x;       // 0..1023
  const int b = tile >> 5;
  const int hw0 = (tile & 31) * 32;
  const float* zb = z + b * (D_ * HW_) + hw0;
#pragma unroll
  for (int r = 0; r < 8; ++r) {
    int ii = r * 256 + tid;          // 0..2047
    int d = ii >> 3, t4s = (ii & 7) * 4;
    float4 v = *(const float4*)(zb + d * HW_ + t4s);
    *(float4*)(zt + d * 32 + t4s) = v;
  }
  __syncthreads();

  const int t4 = (tid & 7) * 4;      // 4 tokens
  const int cgi = tid >> 3;          // 0..31 -> 8 codes per chunk
  float zn[4];
#pragma unroll
  for (int i = 0; i < 4; ++i) zn[i] = znorm[b * HW_ + hw0 + t4 + i];

  float best[4]; int bidx[4];
#pragma unroll
  for (int i = 0; i < 4; ++i) { best[i] = 3.4e38f; bidx[i] = 0; }

  for (int ch = 0; ch < 4; ++ch) {
    const int kb = ch * 256 + cgi * 8;
    const float* e0p = E + kb * D_;
    float acc[4][8];
#pragma unroll
    for (int i = 0; i < 4; ++i)
#pragma unroll
      for (int j = 0; j < 8; ++j) acc[i][j] = 0.f;
    for (int d = 0; d < 256; d += 4) {
      float zv[4][4];                 // [dd][tok]
      float ev[8][4];                 // [code][dd]
#pragma unroll
      for (int dd = 0; dd < 4; ++dd)
        *(float4*)zv[dd] = *(const float4*)(zt + (d + dd) * 32 + t4);
#pragma unroll
      for (int j = 0; j < 8; ++j)
        *(float4*)ev[j] = *(const float4*)(e0p + j * D_ + d);
#pragma unroll
      for (int i = 0; i < 4; ++i)
#pragma unroll
        for (int j = 0; j < 8; ++j) {
          // strict k-order FMA chain (dependence forces sequence)
          float a = acc[i][j];
          a = __fmaf_rn(zv[0][i], ev[j][0], a);
          a = __fmaf_rn(zv[1][i], ev[j][1], a);
          a = __fmaf_rn(zv[2][i], ev[j][2], a);
          a = __fmaf_rn(zv[3][i], ev[j][3], a);
          acc[i][j] = a;
        }
    }
#pragma unroll
    for (int j = 0; j < 8; ++j) {
      int c = kb + j;
      float en = enorm[c];
#pragma unroll
      for (int i = 0; i < 4; ++i) {
        // np: fl(fl(zn - (2z)@E.T) + en); 2*acc exact
        float s = __fadd_rn(__fsub_rn(zn[i], __fmul_rn(2.0f, acc[i][j])), en);
        if (s < best[i]) { best[i] = s; bidx[i] = c; }
      }
    }
  }

#pragma unroll
  for (int i = 0; i < 4; ++i) {
    int t = t4 + i;
    pv[t * 33 + cgi] = best[i];
    pi[t * 33 + cgi] = bidx[i];
  }
  __syncthreads();
  if (tid < 32) {
    float bv = pv[tid * 33]; int bi = pi[tid * 33];
#pragma unroll
    for (int j = 1; j < 32; ++j) {
      float v = pv[tid * 33 + j]; int ii = pi[tid * 33 + j];
      if (v < bv || (v == bv && ii < bi)) { bv = v; bi = ii; }  // np argmin: lowest idx
    }
    idx_out[b * HW_ + hw0 + tid] = bi;
    atomicAdd(&counts[bi], 1.0f);
  }
}

// ---------------- z_q_st + loss + embed_sum + index output (all f32) ----------------
__global__ __launch_bounds__(256, 1) void vq_scatter_v7(
    const float* __restrict__ z, const float* __restrict__ E,
    const int* __restrict__ idx_in, float* __restrict__ embsum,
    float* __restrict__ loss_sum, float* __restrict__ out_zq,
    float* __restrict__ out_idx) {
  __shared__ float zt[256 * 33];     // staged z, overwritten in-place with z_q_st
  __shared__ int idx_s[32];
  __shared__ float wred[4];
  const int tid = threadIdx.x;
  const int tile = blockIdx.x;       // 0..1023
  const int b = tile >> 5;
  const int hw0 = (tile & 31) * 32;
  const float* zb = z + b * (D_ * HW_) + hw0;
  if (tid < 32) {
    int k = idx_in[b * HW_ + hw0 + tid] & 1023;   // clamp: no wild gather ever
    idx_s[tid] = k;
    out_idx[b * HW_ + hw0 + tid] = (float)k;
  }
#pragma unroll
  for (int r = 0; r < 8; ++r) {
    int ii = r * 256 + tid;
    int d = ii >> 3, t4 = (ii & 7) * 4;
    float4 v = *(const float4*)(zb + d * HW_ + t4);
    float* p = zt + d * 33 + t4;
    p[0] = v.x; p[1] = v.y; p[2] = v.z; p[3] = v.w;
  }
  __syncthreads();

  const int w = tid >> 6, lane = tid & 63;
  float lsum = 0.f;
  for (int tt = 0; tt < 8; ++tt) {
    int t = w * 8 + tt;
    int k = idx_s[t];                      // wave-uniform
    const float* Er = E + k * D_;
    float* es = embsum + k * D_;
#pragma unroll
    for (int i = 0; i < 4; ++i) {
      int d = i * 64 + lane;
      float e = Er[d];
      float zv = zt[d * 33 + t];           // unique (t,d) owner -> safe in-place
      float df = __fsub_rn(zv, e);
      lsum += df * df;
      zt[d * 33 + t] = __fadd_rn(zv, __fsub_rn(e, zv));  // ref: z + (z_q - z)
      atomicAdd(es + d, zv);
    }
  }
#pragma unroll
  for (int o = 32; o > 0; o >>= 1) lsum += __shfl_down(lsum, o, 64);
  if (lane == 0) wred[w] = lsum;
  __syncthreads();
  if (tid == 0) atomicAdd(loss_sum, wred[0] + wred[1] + wred[2] + wred[3]);

  float* ob = out_zq + b * (D_ * HW_) + hw0;
#pragma unroll 4
  for (int r = 0; r < 32; ++r) {
    int d = r * 8 + (tid >> 5);
    int t = tid & 31;
    ob[d * HW_ + t] = zt[d * 33 + t];      // coalesced 128B-chunk f32 stores
  }
}

// ---------------- EMA cluster-size + n + loss finalize ----------------
__global__ void vq_newcs_v7(const float* __restrict__ cs_in, const float* __restrict__ counts,
                            float* __restrict__ newcs, float* __restrict__ nsum,
                            const float* __restrict__ loss_sum,
                            float* __restrict__ out_loss, float* __restrict__ out_ncs) {
  int k = blockIdx.x * 256 + threadIdx.x;
  float v = __fadd_rn(__fmul_rn(0.99f, cs_in[k]), __fmul_rn(0.01f, counts[k]));
  newcs[k] = v;
  out_ncs[k] = v;
  float s = v;
#pragma unroll
  for (int o = 32; o > 0; o >>= 1) s += __shfl_down(s, o, 64);
  __shared__ float w[4];
  if ((threadIdx.x & 63) == 0) w[threadIdx.x >> 6] = s;
  __syncthreads();
  if (threadIdx.x == 0) atomicAdd(nsum, w[0] + w[1] + w[2] + w[3]);
  if (k == 0) out_loss[0] = loss_sum[0] * (1.0f / 8388608.0f);
}

// ---------------- new_es + new_embedding ----------------
__global__ void vq_newemb_v7(const float* __restrict__ es_in, const float* __restrict__ embsum,
                             const float* __restrict__ newcs, const float* __restrict__ nsum,
                             float* __restrict__ out_emb, float* __restrict__ out_nes) {
  int k = blockIdx.x, d = threadIdx.x;
  float n = *nsum;
  float cs = (newcs[k] + 1e-5f) / (n + 1024.0f * 1e-5f) * n;   // ref formula order
  float es = __fadd_rn(__fmul_rn(0.99f, es_in[k * D_ + d]),
                       __fmul_rn(0.01f, embsum[k * D_ + d]));
  out_nes[k * D_ + d] = es;
  out_emb[k * D_ + d] = es / cs;
}

extern "C" void kernel_launch(void* const* d_in, const int* in_sizes, int n_in,
                              void* d_out, int out_size, void* d_ws, size_t ws_size,
                              hipStream_t stream) {
  (void)in_sizes; (void)n_in; (void)out_size; (void)ws_size;
  const float* z       = (const float*)d_in[0];   // f32 inputs (per reference dtypes)
  const float* E       = (const float*)d_in[1];
  const float* ema_cs  = (const float*)d_in[2];
  const float* ema_es  = (const float*)d_in[3];
  float* out = (float*)d_out;                      // f32 outputs (reference is f32)
  char* ws = (char*)d_ws;
  int*   ws_idx = (int*)(ws + WS_IDX);
  float* counts = (float*)(ws + WS_COUNTS);
  float* embsum = (float*)(ws + WS_EMBSUM);
  float* loss_s = (float*)(ws + WS_LOSS);
  float* nsum   = (float*)(ws + WS_NSUM);
  float* newcs  = (float*)(ws + WS_NEWCS);
  float* enorm  = (float*)(ws + WS_ENORM);
  float* znorm  = (float*)(ws + WS_ZNORM);

  hipMemsetAsync(d_ws, 0, WS_TOTAL, stream);
  vq_norms_v7<<<dim3(264), dim3(128), 0, stream>>>(z, E, znorm, enorm);
  vq_dist_v7<<<dim3(1024), dim3(256), 0, stream>>>(z, E, znorm, enorm, ws_idx, counts);
  vq_scatter_v7<<<dim3(1024), dim3(256), 0, stream>>>(z, E, ws_idx, embsum, loss_s,
                                                      out + O_ZQ, out + O_IDX);
  vq_newcs_v7<<<dim3(4), dim3(256), 0, stream>>>(ema_cs, counts, newcs, nsum, loss_s,
                                                 out + O_LOSS, out + O_NCS);
  vq_newemb_v7<<<dim3(K_), dim3(256), 0, stream>>>(ema_es, embsum, newcs, nsum,
                                                   out + O_EMB, out + O_NES);
}

// Round 8
// 487.689 us; speedup vs baseline: 1.0541x; 1.0541x over previous
//
#include <hip/hip_runtime.h>

#define D_  256
#define K_  1024
#define HW_ 1024      // 32*32
#define N_  32768     // 32*HW_

// workspace layout (bytes)
#define WS_IDX     0          // int32[32768]
#define WS_COUNTS  131072     // f32[1024]
#define WS_EMBSUM  135168     // f32[262144]
#define WS_LOSS    1183744    // f32
#define WS_NSUM    1183748    // f32
#define WS_NEWCS   1183752    // f32[1024]
#define WS_ENORM   1187848    // f32[1024]
#define WS_ZNORM   1191944    // f32[32768]
#define WS_TOTAL   1323016

// output offsets (f32 elements): (z_q_st, loss, indices, new_emb, new_cs, new_es)
#define O_ZQ   0
#define O_LOSS 8388608
#define O_IDX  8388609
#define O_EMB  8421377
#define O_NCS  8683521
#define O_NES  8684545

// numpy pairwise_sum of 256 squares: two 128-halves, 8 accumulators,
// combine ((r0+r1)+(r2+r3))+((r4+r5)+(r6+r7)). __f*_rn blocks FMA contraction.
__device__ __forceinline__ float pw256_sq(const float* __restrict__ p, int stride) {
  float tot0 = 0.f, tot1 = 0.f;
#pragma unroll
  for (int h = 0; h < 2; ++h) {
    const float* q = p + h * 128 * stride;
    float r[8];
#pragma unroll
    for (int j = 0; j < 8; ++j) { float x = q[j * stride]; r[j] = __fmul_rn(x, x); }
    for (int i = 8; i < 128; i += 8)
#pragma unroll
      for (int j = 0; j < 8; ++j) {
        float x = q[(i + j) * stride];
        r[j] = __fadd_rn(r[j], __fmul_rn(x, x));
      }
    float s = __fadd_rn(__fadd_rn(__fadd_rn(r[0], r[1]), __fadd_rn(r[2], r[3])),
                        __fadd_rn(__fadd_rn(r[4], r[5]), __fadd_rn(r[6], r[7])));
    if (h == 0) tot0 = s; else tot1 = s;
  }
  return __fadd_rn(tot0, tot1);
}

// ---------------- ||z_n||^2 and ||e_k||^2, np summation order ----------------
__global__ void vq_norms_v7(const float* __restrict__ z, const float* __restrict__ E,
                            float* __restrict__ znorm, float* __restrict__ enorm) {
  int t = blockIdx.x * 128 + threadIdx.x;        // 264 x 128 = 33792
  if (t < N_) {
    const float* p = z + (t >> 10) * (D_ * HW_) + (t & 1023);  // stride HW_ over d
    znorm[t] = pw256_sq(p, HW_);
  } else if (t < N_ + K_) {
    enorm[t - N_] = pw256_sq(E + (t - N_) * D_, 1);
  }
}

// ---------------- fused distance-GEMM + argmin ----------------
// 1024 blocks (one per 32-token tile). Microtile 8 tok x 8 codes per thread;
// 2 chunks of 512 codes. Per d-step-4 iter: 16 loads feed 256 FMAs (2x the
// FMA shadow of v7's 12-load/128-FMA) -> L2 latency hidden under FMA issue.
// FMA chain per acc is k-sequential, byte-identical numerics to v7.
__global__ __launch_bounds__(256, 2) void vq_dist_v8(
    const float* __restrict__ z, const float* __restrict__ E,
    const float* __restrict__ znorm, const float* __restrict__ enorm,
    int* __restrict__ idx_out, float* __restrict__ counts) {
  __shared__ float zt[256 * 32];    // [d][t] stride 32 -> 32 KiB
  __shared__ float pv[32 * 65];     // [tok][cg] partial-min values
  __shared__ int   pi[32 * 65];
  const int tid = threadIdx.x;
  const int tile = blockIdx.x;       // 0..1023
  const int b = tile >> 5;
  const int hw0 = (tile & 31) * 32;
  const float* zb = z + b * (D_ * HW_) + hw0;
#pragma unroll
  for (int r = 0; r < 8; ++r) {
    int ii = r * 256 + tid;          // 0..2047
    int d = ii >> 3, t4s = (ii & 7) * 4;
    float4 v = *(const float4*)(zb + d * HW_ + t4s);
    *(float4*)(zt + d * 32 + t4s) = v;
  }
  __syncthreads();

  const int t8 = (tid & 3) * 8;      // 8 tokens
  const int cg = tid >> 2;           // 0..63 -> 8 codes per chunk
  float zn[8];
#pragma unroll
  for (int i = 0; i < 8; ++i) zn[i] = znorm[b * HW_ + hw0 + t8 + i];

  float best[8]; int bidx[8];
#pragma unroll
  for (int i = 0; i < 8; ++i) { best[i] = 3.4e38f; bidx[i] = 0; }

  for (int ch = 0; ch < 2; ++ch) {
    const int kb = ch * 512 + cg * 8;
    const float* e0p = E + kb * D_;
    float acc[8][8];
#pragma unroll
    for (int i = 0; i < 8; ++i)
#pragma unroll
      for (int j = 0; j < 8; ++j) acc[i][j] = 0.f;
    for (int d = 0; d < 256; d += 4) {
      float zv[4][8];                 // [dd][tok]
      float ev[8][4];                 // [code][dd]
#pragma unroll
      for (int dd = 0; dd < 4; ++dd) {
        *(float4*)&zv[dd][0] = *(const float4*)(zt + (d + dd) * 32 + t8);
        *(float4*)&zv[dd][4] = *(const float4*)(zt + (d + dd) * 32 + t8 + 4);
      }
#pragma unroll
      for (int j = 0; j < 8; ++j)
        *(float4*)ev[j] = *(const float4*)(e0p + j * D_ + d);
#pragma unroll
      for (int i = 0; i < 8; ++i)
#pragma unroll
        for (int j = 0; j < 8; ++j) {
          // strict k-order FMA chain (dependence forces sequence)
          float a = acc[i][j];
          a = __fmaf_rn(zv[0][i], ev[j][0], a);
          a = __fmaf_rn(zv[1][i], ev[j][1], a);
          a = __fmaf_rn(zv[2][i], ev[j][2], a);
          a = __fmaf_rn(zv[3][i], ev[j][3], a);
          acc[i][j] = a;
        }
    }
#pragma unroll
    for (int j = 0; j < 8; ++j) {
      int c = kb + j;
      float en = enorm[c];
#pragma unroll
      for (int i = 0; i < 8; ++i) {
        // np: fl(fl(zn - (2z)@E.T) + en); 2*acc exact
        float s = __fadd_rn(__fsub_rn(zn[i], __fmul_rn(2.0f, acc[i][j])), en);
        if (s < best[i]) { best[i] = s; bidx[i] = c; }
      }
    }
  }

#pragma unroll
  for (int i = 0; i < 8; ++i) {
    int t = t8 + i;
    pv[t * 65 + cg] = best[i];
    pi[t * 65 + cg] = bidx[i];
  }
  __syncthreads();
  if (tid < 32) {
    float bv = pv[tid * 65]; int bi = pi[tid * 65];
#pragma unroll 8
    for (int j = 1; j < 64; ++j) {
      float v = pv[tid * 65 + j]; int ii = pi[tid * 65 + j];
      if (v < bv || (v == bv && ii < bi)) { bv = v; bi = ii; }  // np argmin: lowest idx
    }
    idx_out[b * HW_ + hw0 + tid] = bi;
    atomicAdd(&counts[bi], 1.0f);
  }
}

// ---------------- z_q_st + loss + embed_sum + index output (all f32) ----------------
__global__ __launch_bounds__(256, 1) void vq_scatter_v7(
    const float* __restrict__ z, const float* __restrict__ E,
    const int* __restrict__ idx_in, float* __restrict__ embsum,
    float* __restrict__ loss_sum, float* __restrict__ out_zq,
    float* __restrict__ out_idx) {
  __shared__ float zt[256 * 33];     // staged z, overwritten in-place with z_q_st
  __shared__ int idx_s[32];
  __shared__ float wred[4];
  const int tid = threadIdx.x;
  const int tile = blockIdx.x;       // 0..1023
  const int b = tile >> 5;
  const int hw0 = (tile & 31) * 32;
  const float* zb = z + b * (D_ * HW_) + hw0;
  if (tid < 32) {
    int k = idx_in[b * HW_ + hw0 + tid] & 1023;   // clamp: no wild gather ever
    idx_s[tid] = k;
    out_idx[b * HW_ + hw0 + tid] = (float)k;
  }
#pragma unroll
  for (int r = 0; r < 8; ++r) {
    int ii = r * 256 + tid;
    int d = ii >> 3, t4 = (ii & 7) * 4;
    float4 v = *(const float4*)(zb + d * HW_ + t4);
    float* p = zt + d * 33 + t4;
    p[0] = v.x; p[1] = v.y; p[2] = v.z; p[3] = v.w;
  }
  __syncthreads();

  const int w = tid >> 6, lane = tid & 63;
  float lsum = 0.f;
  for (int tt = 0; tt < 8; ++tt) {
    int t = w * 8 + tt;
    int k = idx_s[t];                      // wave-uniform
    const float* Er = E + k * D_;
    float* es = embsum + k * D_;
#pragma unroll
    for (int i = 0; i < 4; ++i) {
      int d = i * 64 + lane;
      float e = Er[d];
      float zv = zt[d * 33 + t];           // unique (t,d) owner -> safe in-place
      float df = __fsub_rn(zv, e);
      lsum += df * df;
      zt[d * 33 + t] = __fadd_rn(zv, __fsub_rn(e, zv));  // ref: z + (z_q - z)
      atomicAdd(es + d, zv);
    }
  }
#pragma unroll
  for (int o = 32; o > 0; o >>= 1) lsum += __shfl_down(lsum, o, 64);
  if (lane == 0) wred[w] = lsum;
  __syncthreads();
  if (tid == 0) atomicAdd(loss_sum, wred[0] + wred[1] + wred[2] + wred[3]);

  float* ob = out_zq + b * (D_ * HW_) + hw0;
#pragma unroll 4
  for (int r = 0; r < 32; ++r) {
    int d = r * 8 + (tid >> 5);
    int t = tid & 31;
    ob[d * HW_ + t] = zt[d * 33 + t];      // coalesced 128B-chunk f32 stores
  }
}

// ---------------- EMA cluster-size + n + loss finalize ----------------
__global__ void vq_newcs_v7(const float* __restrict__ cs_in, const float* __restrict__ counts,
                            float* __restrict__ newcs, float* __restrict__ nsum,
                            const float* __restrict__ loss_sum,
                            float* __restrict__ out_loss, float* __restrict__ out_ncs) {
  int k = blockIdx.x * 256 + threadIdx.x;
  float v = __fadd_rn(__fmul_rn(0.99f, cs_in[k]), __fmul_rn(0.01f, counts[k]));
  newcs[k] = v;
  out_ncs[k] = v;
  float s = v;
#pragma unroll
  for (int o = 32; o > 0; o >>= 1) s += __shfl_down(s, o, 64);
  __shared__ float w[4];
  if ((threadIdx.x & 63) == 0) w[threadIdx.x >> 6] = s;
  __syncthreads();
  if (threadIdx.x == 0) atomicAdd(nsum, w[0] + w[1] + w[2] + w[3]);
  if (k == 0) out_loss[0] = loss_sum[0] * (1.0f / 8388608.0f);
}

// ---------------- new_es + new_embedding ----------------
__global__ void vq_newemb_v7(const float* __restrict__ es_in, const float* __restrict__ embsum,
                             const float* __restrict__ newcs, const float* __restrict__ nsum,
                             float* __restrict__ out_emb, float* __restrict__ out_nes) {
  int k = blockIdx.x, d = threadIdx.x;
  float n = *nsum;
  float cs = (newcs[k] + 1e-5f) / (n + 1024.0f * 1e-5f) * n;   // ref formula order
  float es = __fadd_rn(__fmul_rn(0.99f, es_in[k * D_ + d]),
                       __fmul_rn(0.01f, embsum[k * D_ + d]));
  out_nes[k * D_ + d] = es;
  out_emb[k * D_ + d] = es / cs;
}

extern "C" void kernel_launch(void* const* d_in, const int* in_sizes, int n_in,
                              void* d_out, int out_size, void* d_ws, size_t ws_size,
                              hipStream_t stream) {
  (void)in_sizes; (void)n_in; (void)out_size; (void)ws_size;
  const float* z       = (const float*)d_in[0];
  const float* E       = (const float*)d_in[1];
  const float* ema_cs  = (const float*)d_in[2];
  const float* ema_es  = (const float*)d_in[3];
  float* out = (float*)d_out;
  char* ws = (char*)d_ws;
  int*   ws_idx = (int*)(ws + WS_IDX);
  float* counts = (float*)(ws + WS_COUNTS);
  float* embsum = (float*)(ws + WS_EMBSUM);
  float* loss_s = (float*)(ws + WS_LOSS);
  float* nsum   = (float*)(ws + WS_NSUM);
  float* newcs  = (float*)(ws + WS_NEWCS);
  float* enorm  = (float*)(ws + WS_ENORM);
  float* znorm  = (float*)(ws + WS_ZNORM);

  hipMemsetAsync(d_ws, 0, WS_TOTAL, stream);
  vq_norms_v7<<<dim3(264), dim3(128), 0, stream>>>(z, E, znorm, enorm);
  vq_dist_v8<<<dim3(1024), dim3(256), 0, stream>>>(z, E, znorm, enorm, ws_idx, counts);
  vq_scatter_v7<<<dim3(1024), dim3(256), 0, stream>>>(z, E, ws_idx, embsum, loss_s,
                                                      out + O_ZQ, out + O_IDX);
  vq_newcs_v7<<<dim3(4), dim3(256), 0, stream>>>(ema_cs, counts, newcs, nsum, loss_s,
                                                 out + O_LOSS, out + O_NCS);
  vq_newemb_v7<<<dim3(K_), dim3(256), 0, stream>>>(ema_es, embsum, newcs, nsum,
                                                   out + O_EMB, out + O_NES);
}

// Round 9
// 440.996 us; speedup vs baseline: 1.1657x; 1.1059x over previous
//
#include <hip/hip_runtime.h>

#define D_  256
#define K_  1024
#define HW_ 1024      // 32*32
#define N_  32768     // 32*HW_

// workspace layout (bytes)
#define WS_IDX     0          // int32[32768]
#define WS_COUNTS  131072     // f32[1024]
#define WS_EMBSUM  135168     // f32[262144]
#define WS_LOSS    1183744    // f32
#define WS_NSUM    1183748    // f32
#define WS_NEWCS   1183752    // f32[1024]
#define WS_ENORM   1187848    // f32[1024]
#define WS_ZNORM   1191944    // f32[32768]
#define WS_TOTAL   1323016

// output offsets (f32 elements): (z_q_st, loss, indices, new_emb, new_cs, new_es)
#define O_ZQ   0
#define O_LOSS 8388608
#define O_IDX  8388609
#define O_EMB  8421377
#define O_NCS  8683521
#define O_NES  8684545

// numpy pairwise_sum of 256 squares: two 128-halves, 8 accumulators,
// combine ((r0+r1)+(r2+r3))+((r4+r5)+(r6+r7)). __f*_rn blocks FMA contraction.
__device__ __forceinline__ float pw256_sq(const float* __restrict__ p, int stride) {
  float tot0 = 0.f, tot1 = 0.f;
#pragma unroll
  for (int h = 0; h < 2; ++h) {
    const float* q = p + h * 128 * stride;
    float r[8];
#pragma unroll
    for (int j = 0; j < 8; ++j) { float x = q[j * stride]; r[j] = __fmul_rn(x, x); }
    for (int i = 8; i < 128; i += 8)
#pragma unroll
      for (int j = 0; j < 8; ++j) {
        float x = q[(i + j) * stride];
        r[j] = __fadd_rn(r[j], __fmul_rn(x, x));
      }
    float s = __fadd_rn(__fadd_rn(__fadd_rn(r[0], r[1]), __fadd_rn(r[2], r[3])),
                        __fadd_rn(__fadd_rn(r[4], r[5]), __fadd_rn(r[6], r[7])));
    if (h == 0) tot0 = s; else tot1 = s;
  }
  return __fadd_rn(tot0, tot1);
}

// ---------------- ||z_n||^2 and ||e_k||^2, np summation order ----------------
__global__ void vq_norms_v7(const float* __restrict__ z, const float* __restrict__ E,
                            float* __restrict__ znorm, float* __restrict__ enorm) {
  int t = blockIdx.x * 128 + threadIdx.x;        // 264 x 128 = 33792
  if (t < N_) {
    const float* p = z + (t >> 10) * (D_ * HW_) + (t & 1023);  // stride HW_ over d
    znorm[t] = pw256_sq(p, HW_);
  } else if (t < N_ + K_) {
    enorm[t - N_] = pw256_sq(E + (t - N_) * D_, 1);
  }
}

// ---------------- fused distance-GEMM + argmin ----------------
// 1024 blocks (32-token tile), 8 tok x 8 codes/thread, 2 chunks of 512 codes.
// d unrolled by 8 with ev register PING-PONG: ev loads issued one 256-FMA
// half-block ahead of use -> ~200cy L2 latency hidden under FMA issue.
// FMA chain per acc is k-sequential, byte-identical numerics to v7/v8.
__global__ __launch_bounds__(256, 2) void vq_dist_v9(
    const float* __restrict__ z, const float* __restrict__ E,
    const float* __restrict__ znorm, const float* __restrict__ enorm,
    int* __restrict__ idx_out, float* __restrict__ counts) {
  __shared__ float zt[256 * 32];    // [d][t] stride 32 -> 32 KiB
  __shared__ float pv[32 * 65];     // [tok][cg] partial-min values
  __shared__ int   pi[32 * 65];
  const int tid = threadIdx.x;
  const int tile = blockIdx.x;       // 0..1023
  const int b = tile >> 5;
  const int hw0 = (tile & 31) * 32;
  const float* zb = z + b * (D_ * HW_) + hw0;
#pragma unroll
  for (int r = 0; r < 8; ++r) {
    int ii = r * 256 + tid;          // 0..2047
    int d = ii >> 3, t4s = (ii & 7) * 4;
    float4 v = *(const float4*)(zb + d * HW_ + t4s);
    *(float4*)(zt + d * 32 + t4s) = v;
  }
  __syncthreads();

  const int t8 = (tid & 3) * 8;      // 8 tokens
  const int cg = tid >> 2;           // 0..63 -> 8 codes per chunk
  float zn[8];
#pragma unroll
  for (int i = 0; i < 8; ++i) zn[i] = znorm[b * HW_ + hw0 + t8 + i];

  float best[8]; int bidx[8];
#pragma unroll
  for (int i = 0; i < 8; ++i) { best[i] = 3.4e38f; bidx[i] = 0; }

  for (int ch = 0; ch < 2; ++ch) {
    const int kb = ch * 512 + cg * 8;
    const float* e0p = E + kb * D_;
    float acc[8][8];
#pragma unroll
    for (int i = 0; i < 8; ++i)
#pragma unroll
      for (int j = 0; j < 8; ++j) acc[i][j] = 0.f;

    float eva[8][4], evb[8][4];      // ping-pong ev buffers
#pragma unroll
    for (int j = 0; j < 8; ++j)      // prime: eva <- d=0
      *(float4*)eva[j] = *(const float4*)(e0p + j * D_);

    for (int d = 0; d < 256; d += 8) {
      // issue evb <- d+4 (consumed after 256 FMA issue-cycles)
#pragma unroll
      for (int j = 0; j < 8; ++j)
        *(float4*)evb[j] = *(const float4*)(e0p + j * D_ + d + 4);
      // half 0: FMA with eva (in flight since previous half)
      {
        float zv[4][8];
#pragma unroll
        for (int dd = 0; dd < 4; ++dd) {
          *(float4*)&zv[dd][0] = *(const float4*)(zt + (d + dd) * 32 + t8);
          *(float4*)&zv[dd][4] = *(const float4*)(zt + (d + dd) * 32 + t8 + 4);
        }
#pragma unroll
        for (int i = 0; i < 8; ++i)
#pragma unroll
          for (int j = 0; j < 8; ++j) {
            float a = acc[i][j];
            a = __fmaf_rn(zv[0][i], eva[j][0], a);
            a = __fmaf_rn(zv[1][i], eva[j][1], a);
            a = __fmaf_rn(zv[2][i], eva[j][2], a);
            a = __fmaf_rn(zv[3][i], eva[j][3], a);
            acc[i][j] = a;
          }
      }
      // issue eva <- d+8 (wrapped at the tail; wrapped values never consumed)
      {
        int dn = (d + 8) & 255;
#pragma unroll
        for (int j = 0; j < 8; ++j)
          *(float4*)eva[j] = *(const float4*)(e0p + j * D_ + dn);
      }
      // half 1: FMA with evb
      {
        float zv[4][8];
#pragma unroll
        for (int dd = 0; dd < 4; ++dd) {
          *(float4*)&zv[dd][0] = *(const float4*)(zt + (d + 4 + dd) * 32 + t8);
          *(float4*)&zv[dd][4] = *(const float4*)(zt + (d + 4 + dd) * 32 + t8 + 4);
        }
#pragma unroll
        for (int i = 0; i < 8; ++i)
#pragma unroll
          for (int j = 0; j < 8; ++j) {
            float a = acc[i][j];
            a = __fmaf_rn(zv[0][i], evb[j][0], a);
            a = __fmaf_rn(zv[1][i], evb[j][1], a);
            a = __fmaf_rn(zv[2][i], evb[j][2], a);
            a = __fmaf_rn(zv[3][i], evb[j][3], a);
            acc[i][j] = a;
          }
      }
    }
#pragma unroll
    for (int j = 0; j < 8; ++j) {
      int c = kb + j;
      float en = enorm[c];
#pragma unroll
      for (int i = 0; i < 8; ++i) {
        // np: fl(fl(zn - (2z)@E.T) + en); 2*acc exact
        float s = __fadd_rn(__fsub_rn(zn[i], __fmul_rn(2.0f, acc[i][j])), en);
        if (s < best[i]) { best[i] = s; bidx[i] = c; }
      }
    }
  }

#pragma unroll
  for (int i = 0; i < 8; ++i) {
    int t = t8 + i;
    pv[t * 65 + cg] = best[i];
    pi[t * 65 + cg] = bidx[i];
  }
  __syncthreads();
  if (tid < 32) {
    float bv = pv[tid * 65]; int bi = pi[tid * 65];
#pragma unroll 8
    for (int j = 1; j < 64; ++j) {
      float v = pv[tid * 65 + j]; int ii = pi[tid * 65 + j];
      if (v < bv || (v == bv && ii < bi)) { bv = v; bi = ii; }  // np argmin: lowest idx
    }
    idx_out[b * HW_ + hw0 + tid] = bi;
    atomicAdd(&counts[bi], 1.0f);
  }
}

// ---------------- z_q_st + loss + embed_sum + index output (all f32) ----------------
__global__ __launch_bounds__(256, 1) void vq_scatter_v7(
    const float* __restrict__ z, const float* __restrict__ E,
    const int* __restrict__ idx_in, float* __restrict__ embsum,
    float* __restrict__ loss_sum, float* __restrict__ out_zq,
    float* __restrict__ out_idx) {
  __shared__ float zt[256 * 33];     // staged z, overwritten in-place with z_q_st
  __shared__ int idx_s[32];
  __shared__ float wred[4];
  const int tid = threadIdx.x;
  const int tile = blockIdx.x;       // 0..1023
  const int b = tile >> 5;
  const int hw0 = (tile & 31) * 32;
  const float* zb = z + b * (D_ * HW_) + hw0;
  if (tid < 32) {
    int k = idx_in[b * HW_ + hw0 + tid] & 1023;   // clamp: no wild gather ever
    idx_s[tid] = k;
    out_idx[b * HW_ + hw0 + tid] = (float)k;
  }
#pragma unroll
  for (int r = 0; r < 8; ++r) {
    int ii = r * 256 + tid;
    int d = ii >> 3, t4 = (ii & 7) * 4;
    float4 v = *(const float4*)(zb + d * HW_ + t4);
    float* p = zt + d * 33 + t4;
    p[0] = v.x; p[1] = v.y; p[2] = v.z; p[3] = v.w;
  }
  __syncthreads();

  const int w = tid >> 6, lane = tid & 63;
  float lsum = 0.f;
  for (int tt = 0; tt < 8; ++tt) {
    int t = w * 8 + tt;
    int k = idx_s[t];                      // wave-uniform
    const float* Er = E + k * D_;
    float* es = embsum + k * D_;
#pragma unroll
    for (int i = 0; i < 4; ++i) {
      int d = i * 64 + lane;
      float e = Er[d];
      float zv = zt[d * 33 + t];           // unique (t,d) owner -> safe in-place
      float df = __fsub_rn(zv, e);
      lsum += df * df;
      zt[d * 33 + t] = __fadd_rn(zv, __fsub_rn(e, zv));  // ref: z + (z_q - z)
      atomicAdd(es + d, zv);
    }
  }
#pragma unroll
  for (int o = 32; o > 0; o >>= 1) lsum += __shfl_down(lsum, o, 64);
  if (lane == 0) wred[w] = lsum;
  __syncthreads();
  if (tid == 0) atomicAdd(loss_sum, wred[0] + wred[1] + wred[2] + wred[3]);

  float* ob = out_zq + b * (D_ * HW_) + hw0;
#pragma unroll 4
  for (int r = 0; r < 32; ++r) {
    int d = r * 8 + (tid >> 5);
    int t = tid & 31;
    ob[d * HW_ + t] = zt[d * 33 + t];      // coalesced 128B-chunk f32 stores
  }
}

// ---------------- EMA cluster-size + n + loss finalize ----------------
__global__ void vq_newcs_v7(const float* __restrict__ cs_in, const float* __restrict__ counts,
                            float* __restrict__ newcs, float* __restrict__ nsum,
                            const float* __restrict__ loss_sum,
                            float* __restrict__ out_loss, float* __restrict__ out_ncs) {
  int k = blockIdx.x * 256 + threadIdx.x;
  float v = __fadd_rn(__fmul_rn(0.99f, cs_in[k]), __fmul_rn(0.01f, counts[k]));
  newcs[k] = v;
  out_ncs[k] = v;
  float s = v;
#pragma unroll
  for (int o = 32; o > 0; o >>= 1) s += __shfl_down(s, o, 64);
  __shared__ float w[4];
  if ((threadIdx.x & 63) == 0) w[threadIdx.x >> 6] = s;
  __syncthreads();
  if (threadIdx.x == 0) atomicAdd(nsum, w[0] + w[1] + w[2] + w[3]);
  if (k == 0) out_loss[0] = loss_sum[0] * (1.0f / 8388608.0f);
}

// ---------------- new_es + new_embedding ----------------
__global__ void vq_newemb_v7(const float* __restrict__ es_in, const float* __restrict__ embsum,
                             const float* __restrict__ newcs, const float* __restrict__ nsum,
                             float* __restrict__ out_emb, float* __restrict__ out_nes) {
  int k = blockIdx.x, d = threadIdx.x;
  float n = *nsum;
  float cs = (newcs[k] + 1e-5f) / (n + 1024.0f * 1e-5f) * n;   // ref formula order
  float es = __fadd_rn(__fmul_rn(0.99f, es_in[k * D_ + d]),
                       __fmul_rn(0.01f, embsum[k * D_ + d]));
  out_nes[k * D_ + d] = es;
  out_emb[k * D_ + d] = es / cs;
}

extern "C" void kernel_launch(void* const* d_in, const int* in_sizes, int n_in,
                              void* d_out, int out_size, void* d_ws, size_t ws_size,
                              hipStream_t stream) {
  (void)in_sizes; (void)n_in; (void)out_size; (void)ws_size;
  const float* z       = (const float*)d_in[0];
  const float* E       = (const float*)d_in[1];
  const float* ema_cs  = (const float*)d_in[2];
  const float* ema_es  = (const float*)d_in[3];
  float* out = (float*)d_out;
  char* ws = (char*)d_ws;
  int*   ws_idx = (int*)(ws + WS_IDX);
  float* counts = (float*)(ws + WS_COUNTS);
  float* embsum = (float*)(ws + WS_EMBSUM);
  float* loss_s = (float*)(ws + WS_LOSS);
  float* nsum   = (float*)(ws + WS_NSUM);
  float* newcs  = (float*)(ws + WS_NEWCS);
  float* enorm  = (float*)(ws + WS_ENORM);
  float* znorm  = (float*)(ws + WS_ZNORM);

  hipMemsetAsync(d_ws, 0, WS_TOTAL, stream);
  vq_norms_v7<<<dim3(264), dim3(128), 0, stream>>>(z, E, znorm, enorm);
  vq_dist_v9<<<dim3(1024), dim3(256), 0, stream>>>(z, E, znorm, enorm, ws_idx, counts);
  vq_scatter_v7<<<dim3(1024), dim3(256), 0, stream>>>(z, E, ws_idx, embsum, loss_s,
                                                      out + O_ZQ, out + O_IDX);
  vq_newcs_v7<<<dim3(4), dim3(256), 0, stream>>>(ema_cs, counts, newcs, nsum, loss_s,
                                                 out + O_LOSS, out + O_NCS);
  vq_newemb_v7<<<dim3(K_), dim3(256), 0, stream>>>(ema_es, embsum, newcs, nsum,
                                                   out + O_EMB, out + O_NES);
}